// Round 12
// baseline (469.465 us; speedup 1.0000x reference)
//
#include <hip/hip_runtime.h>
#include <hip/hip_bf16.h>
#include <cstdint>
#include <cstddef>

// Problem constants
#define NT   250000      // total nodes
#define NUU  200000      // users
#define NPP  50000       // products
#define EG   500000      // directed edges
#define E2   1000000     // doubled (undirected)
#define HD   128
#define NBLK_SCAN 977    // ceil(NT/256)
#define NT64 3907        // ceil(NT/64)
#define UT64 3125        // user tiles (200000/64)

// ---------- Workspace layout — total 198,251,728 (proven available r7) ----------
#define CNT2_OFF   0ull            // 1,000,000
#define SPART2_OFF 1000000ull      // 65,536
#define SS2_OFF    1065536ull      // 2,048
#define RPTR2_OFF  1067584ull      // 1,000,004
#define BSUM2_OFF  2067588ull      // 3,908 (+pad)
#define BMAT2_OFF  2071504ull      // 180,224 (16B aligned)
#define COL2_OFF   2251728ull      // 4,000,000
#define X2_OFF     6251728ull      // 64,000,000
#define R1B_OFF    70251728ull     // 64,000,000
#define R2B_OFF    134251728ull    // 64,000,000
#define WS_SPLIT   198251728ull

typedef __hip_bfloat16 bf16;
typedef __attribute__((ext_vector_type(8))) short short8v;
typedef __attribute__((ext_vector_type(4))) float f32x4;

__device__ inline float b2f(short s) { return __builtin_bit_cast(float, ((unsigned)(unsigned short)s) << 16); }
__device__ inline unsigned short f2bf(float f) { return __builtin_bit_cast(unsigned short, __float2bfloat16(f)); }

__global__ __launch_bounds__(256) void k_zero(int* __restrict__ p, int n) {
    for (int i = blockIdx.x * 256 + threadIdx.x; i < n; i += gridDim.x * 256) p[i] = 0;
}

// ---------------- CSR build ----------------
__global__ __launch_bounds__(256) void k_count(const int* __restrict__ ei, int* __restrict__ cnt) {
    for (int e = blockIdx.x * 256 + threadIdx.x; e < E2; e += gridDim.x * 256) {
        int d = (e < EG) ? ei[e + EG] : ei[e - EG];
        atomicAdd(&cnt[d], 1);
    }
}

__global__ __launch_bounds__(256) void k_scan1(const int* __restrict__ cnt, int* __restrict__ bsum) {
    __shared__ int lds[256];
    int i = blockIdx.x * 256 + threadIdx.x;
    int v = (i < NT) ? cnt[i] : 0;
    lds[threadIdx.x] = v; __syncthreads();
    for (int s = 128; s > 0; s >>= 1) {
        if (threadIdx.x < s) lds[threadIdx.x] += lds[threadIdx.x + s];
        __syncthreads();
    }
    if (threadIdx.x == 0) bsum[blockIdx.x] = lds[0];
}

__global__ __launch_bounds__(1024) void k_scan2(int* __restrict__ bsum) {
    __shared__ int lds[1024];
    int i = threadIdx.x;
    int v = (i < NBLK_SCAN) ? bsum[i] : 0;
    lds[i] = v; __syncthreads();
    for (int off = 1; off < 1024; off <<= 1) {
        int t = (i >= off) ? lds[i - off] : 0;
        __syncthreads();
        lds[i] += t;
        __syncthreads();
    }
    if (i < NBLK_SCAN) bsum[i] = lds[i] - v;   // exclusive
}

__global__ __launch_bounds__(256) void k_scan3(const int* __restrict__ cnt, const int* __restrict__ bsum,
                                               int* __restrict__ rp) {
    __shared__ int lds[256];
    int i = blockIdx.x * 256 + threadIdx.x;
    int v = (i < NT) ? cnt[i] : 0;
    lds[threadIdx.x] = v; __syncthreads();
    for (int off = 1; off < 256; off <<= 1) {
        int t = (threadIdx.x >= off) ? lds[threadIdx.x - off] : 0;
        __syncthreads();
        lds[threadIdx.x] += t;
        __syncthreads();
    }
    if (i < NT) rp[i] = bsum[blockIdx.x] + lds[threadIdx.x] - v;
    if (i == 0 && blockIdx.x == 0) rp[NT] = E2;
}

__global__ __launch_bounds__(256) void k_fill(const int* __restrict__ ei, const int* __restrict__ rp,
                                              int* __restrict__ fill, int* __restrict__ col) {
    for (int e = blockIdx.x * 256 + threadIdx.x; e < E2; e += gridDim.x * 256) {
        int s = ei[e];
        int d = (e < EG) ? ei[e + EG] : ei[e - EG];
        int slot = rp[d] + atomicAdd(&fill[d], 1);
        col[slot] = s;
    }
}

// ---------------- Weight conversion: fp32 -> bf16, stacked/padded ----------------
__global__ __launch_bounds__(256) void k_wcvt(const float* __restrict__ W1l, const float* __restrict__ W1r,
                                              const float* __restrict__ W2l, const float* __restrict__ W2r,
                                              const float* __restrict__ Wu, const float* __restrict__ Wp,
                                              bf16* __restrict__ B) {
    int i = blockIdx.x * 256 + threadIdx.x;
    if (i < 65536) {
        int layer = i >> 15, rem = i & 32767, o = rem >> 8, k = rem & 255;
        const float* W = layer ? ((k < 128) ? W2l : W2r) : ((k < 128) ? W1l : W1r);
        B[i] = __float2bfloat16(W[o * 128 + (k & 127)]);
    } else if (i < 81920) {
        int rem = i - 65536, o = rem >> 7, k = rem & 127;
        B[i] = __float2bfloat16((k < 100) ? Wu[o * 100 + k] : 0.f);
    } else if (i < 90112) {
        int rem = i - 81920, o = rem >> 6, k = rem & 63;
        B[i] = __float2bfloat16((k < 50) ? Wp[o * 50 + k] : 0.f);
    }
}

// ---------------- MFMA projection v2: X = relu(in @ Wp^T + b) ----------------
template<int DIN, int KPAD>
__global__ __launch_bounds__(256) void k_projm(const float* __restrict__ in, const bf16* __restrict__ Bp,
                                               const float* __restrict__ bias, bf16* __restrict__ outp,
                                               int nrows, int rowbase) {
    __shared__ __align__(16) char As[128 * KPAD * 2];
    const int tid = threadIdx.x;
    const int tb = blockIdx.x * 128;
    constexpr int RSTRIDE = KPAD * 2;
    constexpr int PADE = KPAD - DIN;
    constexpr int PH = PADE / 2;
    constexpr int PPAD = 128 * PH;
    constexpr int PMAIN = 128 * DIN / 2;

    for (int q = tid; q < PPAD; q += 256) {
        int row = q / PH;
        int k = DIN + (q - row * PH) * 2;
        *(unsigned*)(As + row * RSTRIDE + ((((k >> 3) << 4) ^ ((row & 7) << 4)) + (k & 7) * 2)) = 0u;
    }
    for (int q = tid; q < PMAIN; q += 256) {
        int f = q * 2;
        int row = f / DIN, k = f - row * DIN;
        int rg = tb + row; if (rg > nrows - 1) rg = nrows - 1;
        float2 v = *(const float2*)(in + (size_t)rg * DIN + k);
        unsigned u = (unsigned)f2bf(v.x) | ((unsigned)f2bf(v.y) << 16);
        *(unsigned*)(As + row * RSTRIDE + ((((k >> 3) << 4) ^ ((row & 7) << 4)) + (k & 7) * 2)) = u;
    }
    __syncthreads();

    const int lane = tid & 63, wid = tid >> 6;
    const int wr = wid >> 1, wc = wid & 1;
    const int r15 = lane & 15, l4 = lane >> 4;
    constexpr int NKS = KPAD / 32;
    f32x4 acc[4][4] = {};
#pragma unroll
    for (int ks = 0; ks < NKS; ks++) {
        short8v a[4], b[4];
#pragma unroll
        for (int m = 0; m < 4; m++) {
            int rl = wr * 64 + m * 16 + r15;
            a[m] = *(const short8v*)(As + rl * RSTRIDE + ((ks * 64 + l4 * 16) ^ ((rl & 7) << 4)));
        }
#pragma unroll
        for (int n = 0; n < 4; n++) {
            int c = wc * 64 + n * 16 + r15;
            b[n] = *(const short8v*)(Bp + (size_t)c * KPAD + ks * 32 + l4 * 8);
        }
#pragma unroll
        for (int m = 0; m < 4; m++)
#pragma unroll
            for (int n = 0; n < 4; n++)
                acc[m][n] = __builtin_amdgcn_mfma_f32_16x16x32_bf16(a[m], b[n], acc[m][n], 0, 0, 0);
    }
    float bcol[4];
#pragma unroll
    for (int n = 0; n < 4; n++) bcol[n] = bias[wc * 64 + n * 16 + r15];
#pragma unroll
    for (int m = 0; m < 4; m++)
#pragma unroll
        for (int n = 0; n < 4; n++)
#pragma unroll
            for (int g = 0; g < 4; g++) {
                int row = tb + wr * 64 + m * 16 + l4 * 4 + g;
                if (row < nrows) {
                    float v = fmaxf(acc[m][n][g] + bcol[n], 0.f);
                    outp[(size_t)(rowbase + row) * HD + wc * 64 + n * 16 + r15] = __float2bfloat16(v);
                }
            }
}

// ---------------- Fused SAGE layer, 64-row tiles ----------------
// Tile remap: user tiles [0,3125) and product tiles [3125,3907) interleaved 1-in-5.
// Own-row loads issued FIRST (fly under the entire gather). Phase A: 32 8-lane groups
// gather means into the swizzled 16KB LDS tile. B1 (Wl, K0..127) -> restage own rows
// (+BN fold) -> B2 (Wr, K128..255). Quadrant waves acc[2][4].
template<bool NORM>
__global__ __launch_bounds__(256) void k_layer(const bf16* __restrict__ hin, const float* __restrict__ ssv,
                                               const int* __restrict__ rp, const int* __restrict__ col,
                                               const bf16* __restrict__ Bmat, const float* __restrict__ blv,
                                               bf16* __restrict__ outp, float* __restrict__ spart,
                                               int store_n) {
    int g = blockIdx.x / 5, pos = blockIdx.x % 5;
    int tile = (pos < 4) ? (g * 4 + pos) : (UT64 + g);
    if (pos < 4 && tile >= UT64) return;    // 3 no-op blocks

    __shared__ __align__(16) char At[16384];   // 64 rows x 256B; slot s: row*256 + ((s*16)^((row&7)<<4))
    const int tid = threadIdx.x;
    const int tb = tile * 64;

    // ---- Own-row prefetch (issued first; lands during gather) ----
    const int seg = tid & 15, r0 = tid >> 4;
    const int sfo = seg * 8;
    short8v vh[4];
#pragma unroll
    for (int it = 0; it < 4; it++) {
        int row = r0 + it * 16;
        int r = tb + row; if (r > NT - 1) r = NT - 1;
        vh[it] = *(const short8v*)(hin + (size_t)r * HD + sfo);
    }

    // ---- Phase A: gather means (one node per 8-lane group, 2 rounds) ----
    const int gid = tid >> 3, l8 = tid & 7;
    const int fo = l8 * 8;
    float sva[8], tva[8], svb[8], tvb[8];
    if (NORM) {
#pragma unroll
        for (int j = 0; j < 8; j++) {
            sva[j] = ssv[fo + j];      tva[j] = ssv[HD + fo + j];
            svb[j] = ssv[64 + fo + j]; tvb[j] = ssv[HD + 64 + fo + j];
        }
    }
    for (int q = 0; q < 2; q++) {
        int nl = q * 32 + gid;
        int node = tb + nl;
        int s0 = 0, s1 = 0;
        if (node < NT) { s0 = rp[node]; s1 = rp[node + 1]; }
        float a[8] = {}, b[8] = {};
        for (int p = s0; p < s1; p += 4) {
            int i1 = min(p + 1, s1 - 1), i2 = min(p + 2, s1 - 1), i3 = min(p + 3, s1 - 1);
            int c0 = col[p], c1 = col[i1], c2 = col[i2], c3 = col[i3];
            const bf16* r0p = hin + (size_t)c0 * HD + fo;
            const bf16* r1p = hin + (size_t)c1 * HD + fo;
            const bf16* r2p = hin + (size_t)c2 * HD + fo;
            const bf16* r3p = hin + (size_t)c3 * HD + fo;
            short8v uA0 = *(const short8v*)r0p, uB0 = *(const short8v*)(r0p + 64);
            short8v uA1 = *(const short8v*)r1p, uB1 = *(const short8v*)(r1p + 64);
            short8v uA2 = *(const short8v*)r2p, uB2 = *(const short8v*)(r2p + 64);
            short8v uA3 = *(const short8v*)r3p, uB3 = *(const short8v*)(r3p + 64);
            float m1 = (p + 1 < s1) ? 1.f : 0.f;
            float m2 = (p + 2 < s1) ? 1.f : 0.f;
            float m3 = (p + 3 < s1) ? 1.f : 0.f;
#pragma unroll
            for (int j = 0; j < 8; j++) {
                float vA0 = b2f(uA0[j]), vA1 = b2f(uA1[j]), vA2 = b2f(uA2[j]), vA3 = b2f(uA3[j]);
                float vB0 = b2f(uB0[j]), vB1 = b2f(uB1[j]), vB2 = b2f(uB2[j]), vB3 = b2f(uB3[j]);
                if (NORM) {
                    vA0 = fmaxf(fmaf(vA0, sva[j], tva[j]), 0.f);
                    vA1 = fmaxf(fmaf(vA1, sva[j], tva[j]), 0.f);
                    vA2 = fmaxf(fmaf(vA2, sva[j], tva[j]), 0.f);
                    vA3 = fmaxf(fmaf(vA3, sva[j], tva[j]), 0.f);
                    vB0 = fmaxf(fmaf(vB0, svb[j], tvb[j]), 0.f);
                    vB1 = fmaxf(fmaf(vB1, svb[j], tvb[j]), 0.f);
                    vB2 = fmaxf(fmaf(vB2, svb[j], tvb[j]), 0.f);
                    vB3 = fmaxf(fmaf(vB3, svb[j], tvb[j]), 0.f);
                }
                a[j] += vA0 + m1 * vA1 + m2 * vA2 + m3 * vA3;
                b[j] += vB0 + m1 * vB1 + m2 * vB2 + m3 * vB3;
            }
        }
        float inv = 1.f / (float)max(s1 - s0, 1);
        short8v wa, wb;
#pragma unroll
        for (int j = 0; j < 8; j++) { wa[j] = (short)f2bf(a[j] * inv); wb[j] = (short)f2bf(b[j] * inv); }
        *(short8v*)(At + nl * 256 + ((l8 * 16) ^ ((nl & 7) << 4))) = wa;
        *(short8v*)(At + nl * 256 + (((8 + l8) * 16) ^ ((nl & 7) << 4))) = wb;
    }
    __syncthreads();

    // ---- B1: MFMA on means (K 0..127) ----
    const int lane = tid & 63, wid = tid >> 6;
    const int wr = wid >> 1, wc = wid & 1;
    const int r15 = lane & 15, l4 = lane >> 4;
    f32x4 acc[2][4] = {};
#pragma unroll
    for (int ks = 0; ks < 4; ks++) {
        short8v a[2], b[4];
#pragma unroll
        for (int m = 0; m < 2; m++) {
            int rl = wr * 32 + m * 16 + r15;
            a[m] = *(const short8v*)(At + rl * 256 + ((ks * 64 + l4 * 16) ^ ((rl & 7) << 4)));
        }
#pragma unroll
        for (int n = 0; n < 4; n++) {
            int c = wc * 64 + n * 16 + r15;
            b[n] = *(const short8v*)(Bmat + (size_t)c * 256 + ks * 32 + l4 * 8);
        }
#pragma unroll
        for (int m = 0; m < 2; m++)
#pragma unroll
            for (int n = 0; n < 4; n++)
                acc[m][n] = __builtin_amdgcn_mfma_f32_16x16x32_bf16(a[m], b[n], acc[m][n], 0, 0, 0);
    }
    __syncthreads();   // B1 LDS reads done before restage

    // ---- Restage own rows (+BN fold) ----
    if (NORM) {
        float sv2[8], tv2[8];
#pragma unroll
        for (int j = 0; j < 8; j++) { sv2[j] = ssv[sfo + j]; tv2[j] = ssv[HD + sfo + j]; }
#pragma unroll
        for (int it = 0; it < 4; it++) {
#pragma unroll
            for (int j = 0; j < 8; j++) {
                float f = b2f(vh[it][j]);
                vh[it][j] = (short)f2bf(fmaxf(fmaf(f, sv2[j], tv2[j]), 0.f));
            }
        }
    }
#pragma unroll
    for (int it = 0; it < 4; it++) {
        int row = r0 + it * 16;
        *(short8v*)(At + row * 256 + ((seg * 16) ^ ((row & 7) << 4))) = vh[it];
    }
    __syncthreads();

    // ---- B2: MFMA on own rows (K 128..255) ----
#pragma unroll
    for (int ks = 0; ks < 4; ks++) {
        short8v a[2], b[4];
#pragma unroll
        for (int m = 0; m < 2; m++) {
            int rl = wr * 32 + m * 16 + r15;
            a[m] = *(const short8v*)(At + rl * 256 + ((ks * 64 + l4 * 16) ^ ((rl & 7) << 4)));
        }
#pragma unroll
        for (int n = 0; n < 4; n++) {
            int c = wc * 64 + n * 16 + r15;
            b[n] = *(const short8v*)(Bmat + (size_t)c * 256 + (ks + 4) * 32 + l4 * 8);
        }
#pragma unroll
        for (int m = 0; m < 2; m++)
#pragma unroll
            for (int n = 0; n < 4; n++)
                acc[m][n] = __builtin_amdgcn_mfma_f32_16x16x32_bf16(a[m], b[n], acc[m][n], 0, 0, 0);
    }

    // ---- Epilogue: bias, store, BN stats ----
    float bcol[4];
#pragma unroll
    for (int n = 0; n < 4; n++) bcol[n] = blv[wc * 64 + n * 16 + r15];
    float ls[4] = {0.f, 0.f, 0.f, 0.f}, lq[4] = {0.f, 0.f, 0.f, 0.f};
#pragma unroll
    for (int m = 0; m < 2; m++)
#pragma unroll
        for (int n = 0; n < 4; n++)
#pragma unroll
            for (int gg = 0; gg < 4; gg++) {
                int row = tb + wr * 32 + m * 16 + l4 * 4 + gg;
                float v = acc[m][n][gg] + bcol[n];
                if (row < NT) { ls[n] += v; lq[n] += v * v; }
                if (row < store_n)
                    outp[(size_t)row * HD + wc * 64 + n * 16 + r15] = __float2bfloat16(v);
            }
    int part = (tile & 31) * 256;
#pragma unroll
    for (int n = 0; n < 4; n++) {
        float s = ls[n], q2 = lq[n];
        s  += __shfl_xor(s, 16);  s  += __shfl_xor(s, 32);
        q2 += __shfl_xor(q2, 16); q2 += __shfl_xor(q2, 32);
        if (l4 == 0) {
            atomicAdd(&spart[part + wc * 64 + n * 16 + r15], s);
            atomicAdd(&spart[part + 128 + wc * 64 + n * 16 + r15], q2);
        }
    }
}

// ---------------- BN finalize ----------------
__global__ void k_fin(const float* __restrict__ sp, const float* __restrict__ g,
                      const float* __restrict__ be, float* __restrict__ ssout) {
    int j = threadIdx.x;   // 128
    float m = 0.f, q = 0.f;
    for (int i = 0; i < 32; i++) { m += sp[i * 256 + j]; q += sp[i * 256 + 128 + j]; }
    m *= (1.f / (float)NT);
    q = q * (1.f / (float)NT) - m * m;
    float s = g[j] * rsqrtf(q + 1e-5f);
    ssout[j] = s;
    ssout[HD + j] = be[j] - m * s;
}

// ---------------- Final: out = (relu(bn(raw2)) + x)[:NU] @ Wout^T + bout ----------------
__global__ __launch_bounds__(256) void k_out(const bf16* __restrict__ r2, const float* __restrict__ ss,
                                             const bf16* __restrict__ x, const float* __restrict__ wout,
                                             const float* __restrict__ bout, float* __restrict__ outp) {
    int lane = threadIdx.x & 63;
    int wv = (blockIdx.x * blockDim.x + threadIdx.x) >> 6;
    int nwv = (gridDim.x * blockDim.x) >> 6;
    int g16 = lane >> 4, l16 = lane & 15;
    int fo = l16 * 8;
    float s8[8], t8[8], w8[8];
#pragma unroll
    for (int j = 0; j < 8; j++) {
        s8[j] = ss[fo + j]; t8[j] = ss[HD + fo + j]; w8[j] = wout[fo + j];
    }
    float bo = bout[0];
    for (int r0 = wv * 4; r0 < NUU; r0 += nwv * 4) {
        int row = r0 + g16;
        short8v a  = *(const short8v*)(r2 + (size_t)row * HD + fo);
        short8v xx = *(const short8v*)(x  + (size_t)row * HD + fo);
        float acc = 0.f;
#pragma unroll
        for (int j = 0; j < 8; j++) {
            float h = fmaxf(fmaf(b2f(a[j]), s8[j], t8[j]), 0.f) + b2f(xx[j]);
            acc += h * w8[j];
        }
        acc += __shfl_xor(acc, 1);
        acc += __shfl_xor(acc, 2);
        acc += __shfl_xor(acc, 4);
        acc += __shfl_xor(acc, 8);
        if (l16 == 0) outp[row] = acc + bo;
    }
}

extern "C" void kernel_launch(void* const* d_in, const int* in_sizes, int n_in,
                              void* d_out, int out_size, void* d_ws, size_t ws_size,
                              hipStream_t stream) {
    const float* x_u = (const float*)d_in[0];
    const float* x_p = (const float*)d_in[1];
    const int*   ei  = (const int*)d_in[2];
    const float* W_u = (const float*)d_in[3];
    const float* b_u = (const float*)d_in[4];
    const float* W_p = (const float*)d_in[5];
    const float* b_p = (const float*)d_in[6];
    const float* W1l = (const float*)d_in[7];
    const float* b1l = (const float*)d_in[8];
    const float* W1r = (const float*)d_in[9];
    const float* g1  = (const float*)d_in[10];
    const float* be1 = (const float*)d_in[11];
    const float* W2l = (const float*)d_in[12];
    const float* b2l = (const float*)d_in[13];
    const float* W2r = (const float*)d_in[14];
    const float* g2  = (const float*)d_in[15];
    const float* be2 = (const float*)d_in[16];
    const float* Wout = (const float*)d_in[17];
    const float* bout = (const float*)d_in[18];
    float* out = (float*)d_out;
    char* ws = (char*)d_ws;

    if (ws_size < WS_SPLIT) {   // diagnostic fallback (proven not to trigger in r7)
        k_zero<<<512, 256, 0, stream>>>((int*)d_out, out_size);
        return;
    }

    int*  cnt    = (int*)(ws + CNT2_OFF);
    float* spart = (float*)(ws + SPART2_OFF);
    float* ssbuf = (float*)(ws + SS2_OFF);
    int*  rp     = (int*)(ws + RPTR2_OFF);
    int*  bsum   = (int*)(ws + BSUM2_OFF);
    bf16* Bmat   = (bf16*)(ws + BMAT2_OFF);
    int*  col    = (int*)(ws + COL2_OFF);
    bf16* X      = (bf16*)(ws + X2_OFF);
    bf16* R1     = (bf16*)(ws + R1B_OFF);
    bf16* R2     = (bf16*)(ws + R2B_OFF);

    k_zero<<<1043, 256, 0, stream>>>(cnt, 266896);   // cnt + spart + ss contiguous
    k_wcvt<<<352, 256, 0, stream>>>(W1l, W1r, W2l, W2r, W_u, W_p, Bmat);

    k_count<<<1024, 256, 0, stream>>>(ei, cnt);
    k_scan1<<<NBLK_SCAN, 256, 0, stream>>>(cnt, bsum);
    k_scan2<<<1, 1024, 0, stream>>>(bsum);
    k_scan3<<<NBLK_SCAN, 256, 0, stream>>>(cnt, bsum, rp);
    k_zero<<<977, 256, 0, stream>>>(cnt, NT);
    k_fill<<<1024, 256, 0, stream>>>(ei, rp, cnt, col);

    k_projm<100, 128><<<1563, 256, 0, stream>>>(x_u, Bmat + 65536, b_u, X, NUU, 0);
    k_projm<50, 64><<<391, 256, 0, stream>>>(x_p, Bmat + 81920, b_p, X, NPP, NUU);

    // Layer 1 (fused, 64-row tiles, interleaved product tiles; grid 782*5)
    k_layer<false><<<3910, 256, 0, stream>>>(X, nullptr, rp, col, Bmat, b1l, R1, spart, NT);
    k_fin<<<1, 128, 0, stream>>>(spart, g1, be1, ssbuf);

    // Layer 2
    k_layer<true><<<3910, 256, 0, stream>>>(R1, ssbuf, rp, col, Bmat + 32768, b2l, R2, spart + 8192, NUU);
    k_fin<<<1, 128, 0, stream>>>(spart + 8192, g2, be2, ssbuf + 256);

    k_out<<<1024, 256, 0, stream>>>(R2, ssbuf + 256, X, Wout, bout, out);
}

// Round 13
// 435.203 us; speedup vs baseline: 1.0787x; 1.0787x over previous
//
#include <hip/hip_runtime.h>
#include <hip/hip_bf16.h>
#include <cstdint>
#include <cstddef>

// Problem constants
#define NT   250000      // total nodes
#define NUU  200000      // users
#define NPP  50000       // products
#define EG   500000      // directed edges
#define E2   1000000     // doubled (undirected)
#define HD   128
#define NBLK_SCAN 977    // ceil(NT/256)

// ---------- Workspace layout — total 198,251,728 (proven available r7) ----------
#define CNT2_OFF   0ull            // 1,000,000
#define SPART2_OFF 1000000ull      // 65,536
#define SS2_OFF    1065536ull      // 2,048
#define RPTR2_OFF  1067584ull      // 1,000,004
#define BSUM2_OFF  2067588ull      // 3,908 (+pad)
#define BMAT2_OFF  2071504ull      // 180,224 (16B aligned)
#define COL2_OFF   2251728ull      // 4,000,000
#define X2_OFF     6251728ull      // 64,000,000
#define R1B_OFF    70251728ull     // 64,000,000
#define R2B_OFF    134251728ull    // 64,000,000
#define WS_SPLIT   198251728ull

typedef __hip_bfloat16 bf16;
typedef __attribute__((ext_vector_type(8))) short short8v;
typedef __attribute__((ext_vector_type(4))) float f32x4;

__device__ inline float b2f(short s) { return __builtin_bit_cast(float, ((unsigned)(unsigned short)s) << 16); }
__device__ inline unsigned short f2bf(float f) { return __builtin_bit_cast(unsigned short, __float2bfloat16(f)); }

__global__ __launch_bounds__(256) void k_zero(int* __restrict__ p, int n) {
    for (int i = blockIdx.x * 256 + threadIdx.x; i < n; i += gridDim.x * 256) p[i] = 0;
}

// ---------------- CSR build ----------------
__global__ __launch_bounds__(256) void k_count(const int* __restrict__ ei, int* __restrict__ cnt) {
    for (int e = blockIdx.x * 256 + threadIdx.x; e < E2; e += gridDim.x * 256) {
        int d = (e < EG) ? ei[e + EG] : ei[e - EG];
        atomicAdd(&cnt[d], 1);
    }
}

__global__ __launch_bounds__(256) void k_scan1(const int* __restrict__ cnt, int* __restrict__ bsum) {
    __shared__ int lds[256];
    int i = blockIdx.x * 256 + threadIdx.x;
    int v = (i < NT) ? cnt[i] : 0;
    lds[threadIdx.x] = v; __syncthreads();
    for (int s = 128; s > 0; s >>= 1) {
        if (threadIdx.x < s) lds[threadIdx.x] += lds[threadIdx.x + s];
        __syncthreads();
    }
    if (threadIdx.x == 0) bsum[blockIdx.x] = lds[0];
}

__global__ __launch_bounds__(1024) void k_scan2(int* __restrict__ bsum) {
    __shared__ int lds[1024];
    int i = threadIdx.x;
    int v = (i < NBLK_SCAN) ? bsum[i] : 0;
    lds[i] = v; __syncthreads();
    for (int off = 1; off < 1024; off <<= 1) {
        int t = (i >= off) ? lds[i - off] : 0;
        __syncthreads();
        lds[i] += t;
        __syncthreads();
    }
    if (i < NBLK_SCAN) bsum[i] = lds[i] - v;   // exclusive
}

__global__ __launch_bounds__(256) void k_scan3(const int* __restrict__ cnt, const int* __restrict__ bsum,
                                               int* __restrict__ rp) {
    __shared__ int lds[256];
    int i = blockIdx.x * 256 + threadIdx.x;
    int v = (i < NT) ? cnt[i] : 0;
    lds[threadIdx.x] = v; __syncthreads();
    for (int off = 1; off < 256; off <<= 1) {
        int t = (threadIdx.x >= off) ? lds[threadIdx.x - off] : 0;
        __syncthreads();
        lds[threadIdx.x] += t;
        __syncthreads();
    }
    if (i < NT) rp[i] = bsum[blockIdx.x] + lds[threadIdx.x] - v;
    if (i == 0 && blockIdx.x == 0) rp[NT] = E2;
}

__global__ __launch_bounds__(256) void k_fill(const int* __restrict__ ei, const int* __restrict__ rp,
                                              int* __restrict__ fill, int* __restrict__ col) {
    for (int e = blockIdx.x * 256 + threadIdx.x; e < E2; e += gridDim.x * 256) {
        int s = ei[e];
        int d = (e < EG) ? ei[e + EG] : ei[e - EG];
        int slot = rp[d] + atomicAdd(&fill[d], 1);
        col[slot] = s;
    }
}

// ---------------- Weight conversion: fp32 -> bf16, stacked/padded ----------------
__global__ __launch_bounds__(256) void k_wcvt(const float* __restrict__ W1l, const float* __restrict__ W1r,
                                              const float* __restrict__ W2l, const float* __restrict__ W2r,
                                              const float* __restrict__ Wu, const float* __restrict__ Wp,
                                              bf16* __restrict__ B) {
    int i = blockIdx.x * 256 + threadIdx.x;
    if (i < 65536) {
        int layer = i >> 15, rem = i & 32767, o = rem >> 8, k = rem & 255;
        const float* W = layer ? ((k < 128) ? W2l : W2r) : ((k < 128) ? W1l : W1r);
        B[i] = __float2bfloat16(W[o * 128 + (k & 127)]);
    } else if (i < 81920) {
        int rem = i - 65536, o = rem >> 7, k = rem & 127;
        B[i] = __float2bfloat16((k < 100) ? Wu[o * 100 + k] : 0.f);
    } else if (i < 90112) {
        int rem = i - 81920, o = rem >> 6, k = rem & 63;
        B[i] = __float2bfloat16((k < 50) ? Wp[o * 50 + k] : 0.f);
    }
}

// ---------------- MFMA projection v2: X = relu(in @ Wp^T + b) ----------------
template<int DIN, int KPAD>
__global__ __launch_bounds__(256) void k_projm(const float* __restrict__ in, const bf16* __restrict__ Bp,
                                               const float* __restrict__ bias, bf16* __restrict__ outp,
                                               int nrows, int rowbase) {
    __shared__ __align__(16) char As[128 * KPAD * 2];
    const int tid = threadIdx.x;
    const int tb = blockIdx.x * 128;
    constexpr int RSTRIDE = KPAD * 2;
    constexpr int PADE = KPAD - DIN;
    constexpr int PH = PADE / 2;
    constexpr int PPAD = 128 * PH;
    constexpr int PMAIN = 128 * DIN / 2;

    for (int q = tid; q < PPAD; q += 256) {
        int row = q / PH;
        int k = DIN + (q - row * PH) * 2;
        *(unsigned*)(As + row * RSTRIDE + ((((k >> 3) << 4) ^ ((row & 7) << 4)) + (k & 7) * 2)) = 0u;
    }
    for (int q = tid; q < PMAIN; q += 256) {
        int f = q * 2;
        int row = f / DIN, k = f - row * DIN;
        int rg = tb + row; if (rg > nrows - 1) rg = nrows - 1;
        float2 v = *(const float2*)(in + (size_t)rg * DIN + k);
        unsigned u = (unsigned)f2bf(v.x) | ((unsigned)f2bf(v.y) << 16);
        *(unsigned*)(As + row * RSTRIDE + ((((k >> 3) << 4) ^ ((row & 7) << 4)) + (k & 7) * 2)) = u;
    }
    __syncthreads();

    const int lane = tid & 63, wid = tid >> 6;
    const int wr = wid >> 1, wc = wid & 1;
    const int r15 = lane & 15, l4 = lane >> 4;
    constexpr int NKS = KPAD / 32;
    f32x4 acc[4][4] = {};
#pragma unroll
    for (int ks = 0; ks < NKS; ks++) {
        short8v a[4], b[4];
#pragma unroll
        for (int m = 0; m < 4; m++) {
            int rl = wr * 64 + m * 16 + r15;
            a[m] = *(const short8v*)(As + rl * RSTRIDE + ((ks * 64 + l4 * 16) ^ ((rl & 7) << 4)));
        }
#pragma unroll
        for (int n = 0; n < 4; n++) {
            int c = wc * 64 + n * 16 + r15;
            b[n] = *(const short8v*)(Bp + (size_t)c * KPAD + ks * 32 + l4 * 8);
        }
#pragma unroll
        for (int m = 0; m < 4; m++)
#pragma unroll
            for (int n = 0; n < 4; n++)
                acc[m][n] = __builtin_amdgcn_mfma_f32_16x16x32_bf16(a[m], b[n], acc[m][n], 0, 0, 0);
    }
    float bcol[4];
#pragma unroll
    for (int n = 0; n < 4; n++) bcol[n] = bias[wc * 64 + n * 16 + r15];
#pragma unroll
    for (int m = 0; m < 4; m++)
#pragma unroll
        for (int n = 0; n < 4; n++)
#pragma unroll
            for (int g = 0; g < 4; g++) {
                int row = tb + wr * 64 + m * 16 + l4 * 4 + g;
                if (row < nrows) {
                    float v = fmaxf(acc[m][n][g] + bcol[n], 0.f);
                    outp[(size_t)(rowbase + row) * HD + wc * 64 + n * 16 + r15] = __float2bfloat16(v);
                }
            }
}

// ---------------- Fused SAGE layer: work-stealing gather -> LDS -> split-K MFMA ----------------
// 128-row tiles (r11 geometry). Gather nodes assigned DYNAMICALLY via an LDS atomic
// counter (one node per 8-lane group per pop) — removes the intra-block convoy on the
// degree-imbalanced static assignment. rp pre-staged in LDS. Own-row loads issued
// after gather (fly under B1). B1 (Wl) -> restage own rows (+BN) -> B2 (Wr).
template<bool NORM>
__global__ __launch_bounds__(256) void k_layer(const bf16* __restrict__ hin, const float* __restrict__ ssv,
                                               const int* __restrict__ rp, const int* __restrict__ col,
                                               const bf16* __restrict__ Bmat, const float* __restrict__ blv,
                                               bf16* __restrict__ outp, float* __restrict__ spart,
                                               int store_n) {
    __shared__ __align__(16) char At[32768];   // 128 rows x 256B; slot s: row*256 + ((s*16)^((row&7)<<4))
    __shared__ int rpl[129];
    __shared__ int ctr;
    const int tid = threadIdx.x;
    const int tb = blockIdx.x * 128;

    if (tid < 129) rpl[tid] = rp[min(tb + tid, NT)];   // clamped: rows >= NT get s0==s1 (deg 0)
    if (tid == 255) ctr = 0;
    __syncthreads();

    // ---- Phase A: work-stealing gather (one node per 8-lane group per pop) ----
    const int lane = tid & 63;
    const int l8 = tid & 7;
    const int fo = l8 * 8;
    float sva[8], tva[8], svb[8], tvb[8];
    if (NORM) {
#pragma unroll
        for (int j = 0; j < 8; j++) {
            sva[j] = ssv[fo + j];      tva[j] = ssv[HD + fo + j];
            svb[j] = ssv[64 + fo + j]; tvb[j] = ssv[HD + 64 + fo + j];
        }
    }
    for (;;) {
        int nl = 0;
        if (l8 == 0) nl = atomicAdd(&ctr, 1);
        nl = __shfl(nl, lane & 56);            // broadcast from group leader
        if (nl >= 128) break;
        int s0 = rpl[nl], s1 = rpl[nl + 1];
        float a[8] = {}, b[8] = {};
        for (int p = s0; p < s1; p += 4) {
            int i1 = min(p + 1, s1 - 1), i2 = min(p + 2, s1 - 1), i3 = min(p + 3, s1 - 1);
            int c0 = col[p], c1 = col[i1], c2 = col[i2], c3 = col[i3];
            const bf16* r0p = hin + (size_t)c0 * HD + fo;
            const bf16* r1p = hin + (size_t)c1 * HD + fo;
            const bf16* r2p = hin + (size_t)c2 * HD + fo;
            const bf16* r3p = hin + (size_t)c3 * HD + fo;
            short8v uA0 = *(const short8v*)r0p, uB0 = *(const short8v*)(r0p + 64);
            short8v uA1 = *(const short8v*)r1p, uB1 = *(const short8v*)(r1p + 64);
            short8v uA2 = *(const short8v*)r2p, uB2 = *(const short8v*)(r2p + 64);
            short8v uA3 = *(const short8v*)r3p, uB3 = *(const short8v*)(r3p + 64);
            float m1 = (p + 1 < s1) ? 1.f : 0.f;
            float m2 = (p + 2 < s1) ? 1.f : 0.f;
            float m3 = (p + 3 < s1) ? 1.f : 0.f;
#pragma unroll
            for (int j = 0; j < 8; j++) {
                float vA0 = b2f(uA0[j]), vA1 = b2f(uA1[j]), vA2 = b2f(uA2[j]), vA3 = b2f(uA3[j]);
                float vB0 = b2f(uB0[j]), vB1 = b2f(uB1[j]), vB2 = b2f(uB2[j]), vB3 = b2f(uB3[j]);
                if (NORM) {
                    vA0 = fmaxf(fmaf(vA0, sva[j], tva[j]), 0.f);
                    vA1 = fmaxf(fmaf(vA1, sva[j], tva[j]), 0.f);
                    vA2 = fmaxf(fmaf(vA2, sva[j], tva[j]), 0.f);
                    vA3 = fmaxf(fmaf(vA3, sva[j], tva[j]), 0.f);
                    vB0 = fmaxf(fmaf(vB0, svb[j], tvb[j]), 0.f);
                    vB1 = fmaxf(fmaf(vB1, svb[j], tvb[j]), 0.f);
                    vB2 = fmaxf(fmaf(vB2, svb[j], tvb[j]), 0.f);
                    vB3 = fmaxf(fmaf(vB3, svb[j], tvb[j]), 0.f);
                }
                a[j] += vA0 + m1 * vA1 + m2 * vA2 + m3 * vA3;
                b[j] += vB0 + m1 * vB1 + m2 * vB2 + m3 * vB3;
            }
        }
        float inv = 1.f / (float)max(s1 - s0, 1);
        short8v wa, wb;
#pragma unroll
        for (int j = 0; j < 8; j++) { wa[j] = (short)f2bf(a[j] * inv); wb[j] = (short)f2bf(b[j] * inv); }
        *(short8v*)(At + nl * 256 + ((l8 * 16) ^ ((nl & 7) << 4))) = wa;
        *(short8v*)(At + nl * 256 + (((8 + l8) * 16) ^ ((nl & 7) << 4))) = wb;
    }

    // ---- Issue own-row loads now; they land during B1 ----
    const int seg = tid & 15, r0 = tid >> 4;
    const int sfo = seg * 8;
    short8v vh[8];
#pragma unroll
    for (int it = 0; it < 8; it++) {
        int row = r0 + it * 16;
        int r = tb + row; if (r > NT - 1) r = NT - 1;
        vh[it] = *(const short8v*)(hin + (size_t)r * HD + sfo);
    }
    __syncthreads();

    // ---- B1: MFMA on means (K 0..127) ----
    const int wid = tid >> 6;
    const int wr = wid >> 1, wc = wid & 1;
    const int r15 = lane & 15, l4 = lane >> 4;
    f32x4 acc[4][4] = {};
#pragma unroll
    for (int ks = 0; ks < 4; ks++) {
        short8v a[4], b[4];
#pragma unroll
        for (int m = 0; m < 4; m++) {
            int rl = wr * 64 + m * 16 + r15;
            a[m] = *(const short8v*)(At + rl * 256 + ((ks * 64 + l4 * 16) ^ ((rl & 7) << 4)));
        }
#pragma unroll
        for (int n = 0; n < 4; n++) {
            int c = wc * 64 + n * 16 + r15;
            b[n] = *(const short8v*)(Bmat + (size_t)c * 256 + ks * 32 + l4 * 8);
        }
#pragma unroll
        for (int m = 0; m < 4; m++)
#pragma unroll
            for (int n = 0; n < 4; n++)
                acc[m][n] = __builtin_amdgcn_mfma_f32_16x16x32_bf16(a[m], b[n], acc[m][n], 0, 0, 0);
    }
    __syncthreads();   // B1 LDS reads done before restage

    // ---- Restage own rows (+BN fold) ----
    if (NORM) {
        float sv2[8], tv2[8];
#pragma unroll
        for (int j = 0; j < 8; j++) { sv2[j] = ssv[sfo + j]; tv2[j] = ssv[HD + sfo + j]; }
#pragma unroll
        for (int it = 0; it < 8; it++) {
#pragma unroll
            for (int j = 0; j < 8; j++) {
                float f = b2f(vh[it][j]);
                vh[it][j] = (short)f2bf(fmaxf(fmaf(f, sv2[j], tv2[j]), 0.f));
            }
        }
    }
#pragma unroll
    for (int it = 0; it < 8; it++) {
        int row = r0 + it * 16;
        *(short8v*)(At + row * 256 + ((seg * 16) ^ ((row & 7) << 4))) = vh[it];
    }
    __syncthreads();

    // ---- B2: MFMA on own rows (K 128..255) ----
#pragma unroll
    for (int ks = 0; ks < 4; ks++) {
        short8v a[4], b[4];
#pragma unroll
        for (int m = 0; m < 4; m++) {
            int rl = wr * 64 + m * 16 + r15;
            a[m] = *(const short8v*)(At + rl * 256 + ((ks * 64 + l4 * 16) ^ ((rl & 7) << 4)));
        }
#pragma unroll
        for (int n = 0; n < 4; n++) {
            int c = wc * 64 + n * 16 + r15;
            b[n] = *(const short8v*)(Bmat + (size_t)c * 256 + (ks + 4) * 32 + l4 * 8);
        }
#pragma unroll
        for (int m = 0; m < 4; m++)
#pragma unroll
            for (int n = 0; n < 4; n++)
                acc[m][n] = __builtin_amdgcn_mfma_f32_16x16x32_bf16(a[m], b[n], acc[m][n], 0, 0, 0);
    }

    // ---- Epilogue: bias, store, BN stats ----
    float bcol[4];
#pragma unroll
    for (int n = 0; n < 4; n++) bcol[n] = blv[wc * 64 + n * 16 + r15];
    float ls[4] = {0.f, 0.f, 0.f, 0.f}, lq[4] = {0.f, 0.f, 0.f, 0.f};
#pragma unroll
    for (int m = 0; m < 4; m++)
#pragma unroll
        for (int n = 0; n < 4; n++)
#pragma unroll
            for (int gg = 0; gg < 4; gg++) {
                int row = tb + wr * 64 + m * 16 + l4 * 4 + gg;
                float v = acc[m][n][gg] + bcol[n];
                if (row < NT) { ls[n] += v; lq[n] += v * v; }
                if (row < store_n)
                    outp[(size_t)row * HD + wc * 64 + n * 16 + r15] = __float2bfloat16(v);
            }
    int part = (blockIdx.x & 31) * 256;
#pragma unroll
    for (int n = 0; n < 4; n++) {
        float s = ls[n], q2 = lq[n];
        s  += __shfl_xor(s, 16);  s  += __shfl_xor(s, 32);
        q2 += __shfl_xor(q2, 16); q2 += __shfl_xor(q2, 32);
        if (l4 == 0) {
            atomicAdd(&spart[part + wc * 64 + n * 16 + r15], s);
            atomicAdd(&spart[part + 128 + wc * 64 + n * 16 + r15], q2);
        }
    }
}

// ---------------- BN finalize ----------------
__global__ void k_fin(const float* __restrict__ sp, const float* __restrict__ g,
                      const float* __restrict__ be, float* __restrict__ ssout) {
    int j = threadIdx.x;   // 128
    float m = 0.f, q = 0.f;
    for (int i = 0; i < 32; i++) { m += sp[i * 256 + j]; q += sp[i * 256 + 128 + j]; }
    m *= (1.f / (float)NT);
    q = q * (1.f / (float)NT) - m * m;
    float s = g[j] * rsqrtf(q + 1e-5f);
    ssout[j] = s;
    ssout[HD + j] = be[j] - m * s;
}

// ---------------- Final: out = (relu(bn(raw2)) + x)[:NU] @ Wout^T + bout ----------------
__global__ __launch_bounds__(256) void k_out(const bf16* __restrict__ r2, const float* __restrict__ ss,
                                             const bf16* __restrict__ x, const float* __restrict__ wout,
                                             const float* __restrict__ bout, float* __restrict__ outp) {
    int lane = threadIdx.x & 63;
    int wv = (blockIdx.x * blockDim.x + threadIdx.x) >> 6;
    int nwv = (gridDim.x * blockDim.x) >> 6;
    int g16 = lane >> 4, l16 = lane & 15;
    int fo = l16 * 8;
    float s8[8], t8[8], w8[8];
#pragma unroll
    for (int j = 0; j < 8; j++) {
        s8[j] = ss[fo + j]; t8[j] = ss[HD + fo + j]; w8[j] = wout[fo + j];
    }
    float bo = bout[0];
    for (int r0 = wv * 4; r0 < NUU; r0 += nwv * 4) {
        int row = r0 + g16;
        short8v a  = *(const short8v*)(r2 + (size_t)row * HD + fo);
        short8v xx = *(const short8v*)(x  + (size_t)row * HD + fo);
        float acc = 0.f;
#pragma unroll
        for (int j = 0; j < 8; j++) {
            float h = fmaxf(fmaf(b2f(a[j]), s8[j], t8[j]), 0.f) + b2f(xx[j]);
            acc += h * w8[j];
        }
        acc += __shfl_xor(acc, 1);
        acc += __shfl_xor(acc, 2);
        acc += __shfl_xor(acc, 4);
        acc += __shfl_xor(acc, 8);
        if (l16 == 0) outp[row] = acc + bo;
    }
}

extern "C" void kernel_launch(void* const* d_in, const int* in_sizes, int n_in,
                              void* d_out, int out_size, void* d_ws, size_t ws_size,
                              hipStream_t stream) {
    const float* x_u = (const float*)d_in[0];
    const float* x_p = (const float*)d_in[1];
    const int*   ei  = (const int*)d_in[2];
    const float* W_u = (const float*)d_in[3];
    const float* b_u = (const float*)d_in[4];
    const float* W_p = (const float*)d_in[5];
    const float* b_p = (const float*)d_in[6];
    const float* W1l = (const float*)d_in[7];
    const float* b1l = (const float*)d_in[8];
    const float* W1r = (const float*)d_in[9];
    const float* g1  = (const float*)d_in[10];
    const float* be1 = (const float*)d_in[11];
    const float* W2l = (const float*)d_in[12];
    const float* b2l = (const float*)d_in[13];
    const float* W2r = (const float*)d_in[14];
    const float* g2  = (const float*)d_in[15];
    const float* be2 = (const float*)d_in[16];
    const float* Wout = (const float*)d_in[17];
    const float* bout = (const float*)d_in[18];
    float* out = (float*)d_out;
    char* ws = (char*)d_ws;

    if (ws_size < WS_SPLIT) {   // diagnostic fallback (proven not to trigger in r7)
        k_zero<<<512, 256, 0, stream>>>((int*)d_out, out_size);
        return;
    }

    int*  cnt    = (int*)(ws + CNT2_OFF);
    float* spart = (float*)(ws + SPART2_OFF);
    float* ssbuf = (float*)(ws + SS2_OFF);
    int*  rp     = (int*)(ws + RPTR2_OFF);
    int*  bsum   = (int*)(ws + BSUM2_OFF);
    bf16* Bmat   = (bf16*)(ws + BMAT2_OFF);
    int*  col    = (int*)(ws + COL2_OFF);
    bf16* X      = (bf16*)(ws + X2_OFF);
    bf16* R1     = (bf16*)(ws + R1B_OFF);
    bf16* R2     = (bf16*)(ws + R2B_OFF);

    k_zero<<<1043, 256, 0, stream>>>(cnt, 266896);   // cnt + spart + ss contiguous
    k_wcvt<<<352, 256, 0, stream>>>(W1l, W1r, W2l, W2r, W_u, W_p, Bmat);

    k_count<<<1024, 256, 0, stream>>>(ei, cnt);
    k_scan1<<<NBLK_SCAN, 256, 0, stream>>>(cnt, bsum);
    k_scan2<<<1, 1024, 0, stream>>>(bsum);
    k_scan3<<<NBLK_SCAN, 256, 0, stream>>>(cnt, bsum, rp);
    k_zero<<<977, 256, 0, stream>>>(cnt, NT);
    k_fill<<<1024, 256, 0, stream>>>(ei, rp, cnt, col);

    k_projm<100, 128><<<1563, 256, 0, stream>>>(x_u, Bmat + 65536, b_u, X, NUU, 0);
    k_projm<50, 64><<<391, 256, 0, stream>>>(x_p, Bmat + 81920, b_p, X, NPP, NUU);

    // Layer 1 (fused, 128-row tiles, work-stealing gather)
    k_layer<false><<<1954, 256, 0, stream>>>(X, nullptr, rp, col, Bmat, b1l, R1, spart, NT);
    k_fin<<<1, 128, 0, stream>>>(spart, g1, be1, ssbuf);

    // Layer 2
    k_layer<true><<<1954, 256, 0, stream>>>(R1, ssbuf, rp, col, Bmat + 32768, b2l, R2, spart + 8192, NUU);
    k_fin<<<1, 128, 0, stream>>>(spart + 8192, g2, be2, ssbuf + 256);

    k_out<<<1024, 256, 0, stream>>>(R2, ssbuf + 256, X, Wout, bout, out);
}

// Round 14
// 416.227 us; speedup vs baseline: 1.1279x; 1.0456x over previous
//
#include <hip/hip_runtime.h>
#include <hip/hip_bf16.h>
#include <cstdint>
#include <cstddef>

// Problem constants
#define NT   250000      // total nodes
#define NUU  200000      // users
#define NPP  50000       // products
#define EG   500000      // directed edges
#define E2   1000000     // doubled (undirected)
#define HD   128
#define NBLK_SCAN 977    // ceil(NT/256)

// ---------- Workspace layout — total 198,251,728 (proven available r7) ----------
#define CNT2_OFF   0ull            // 1,000,000
#define SPART2_OFF 1000000ull      // 65,536
#define SS2_OFF    1065536ull      // 2,048
#define RPTR2_OFF  1067584ull      // 1,000,004
#define BSUM2_OFF  2067588ull      // 3,908 (+pad)
#define BMAT2_OFF  2071504ull      // 180,224 (16B aligned)
#define COL2_OFF   2251728ull      // 4,000,000
#define X2_OFF     6251728ull      // 64,000,000
#define R1B_OFF    70251728ull     // 64,000,000
#define R2B_OFF    134251728ull    // 64,000,000
#define WS_SPLIT   198251728ull

typedef __hip_bfloat16 bf16;
typedef __attribute__((ext_vector_type(8))) short short8v;
typedef __attribute__((ext_vector_type(4))) float f32x4;

__device__ inline float b2f(short s) { return __builtin_bit_cast(float, ((unsigned)(unsigned short)s) << 16); }
__device__ inline unsigned short f2bf(float f) { return __builtin_bit_cast(unsigned short, __float2bfloat16(f)); }

__global__ __launch_bounds__(256) void k_zero(int* __restrict__ p, int n) {
    for (int i = blockIdx.x * 256 + threadIdx.x; i < n; i += gridDim.x * 256) p[i] = 0;
}

// ---------------- CSR build (one pass over base edges, both directions) ----------------
__global__ __launch_bounds__(256) void k_count(const int* __restrict__ ei, int* __restrict__ cnt) {
    for (int e = blockIdx.x * 256 + threadIdx.x; e < EG; e += gridDim.x * 256) {
        int s = ei[e], d = ei[e + EG];
        atomicAdd(&cnt[d], 1);
        atomicAdd(&cnt[s], 1);
    }
}

__global__ __launch_bounds__(256) void k_scan1(const int* __restrict__ cnt, int* __restrict__ bsum) {
    __shared__ int lds[256];
    int i = blockIdx.x * 256 + threadIdx.x;
    int v = (i < NT) ? cnt[i] : 0;
    lds[threadIdx.x] = v; __syncthreads();
    for (int s = 128; s > 0; s >>= 1) {
        if (threadIdx.x < s) lds[threadIdx.x] += lds[threadIdx.x + s];
        __syncthreads();
    }
    if (threadIdx.x == 0) bsum[blockIdx.x] = lds[0];
}

__global__ __launch_bounds__(1024) void k_scan2(int* __restrict__ bsum) {
    __shared__ int lds[1024];
    int i = threadIdx.x;
    int v = (i < NBLK_SCAN) ? bsum[i] : 0;
    lds[i] = v; __syncthreads();
    for (int off = 1; off < 1024; off <<= 1) {
        int t = (i >= off) ? lds[i - off] : 0;
        __syncthreads();
        lds[i] += t;
        __syncthreads();
    }
    if (i < NBLK_SCAN) bsum[i] = lds[i] - v;   // exclusive
}

__global__ __launch_bounds__(256) void k_scan3(const int* __restrict__ cnt, const int* __restrict__ bsum,
                                               int* __restrict__ rp) {
    __shared__ int lds[256];
    int i = blockIdx.x * 256 + threadIdx.x;
    int v = (i < NT) ? cnt[i] : 0;
    lds[threadIdx.x] = v; __syncthreads();
    for (int off = 1; off < 256; off <<= 1) {
        int t = (threadIdx.x >= off) ? lds[threadIdx.x - off] : 0;
        __syncthreads();
        lds[threadIdx.x] += t;
        __syncthreads();
    }
    if (i < NT) rp[i] = bsum[blockIdx.x] + lds[threadIdx.x] - v;
    if (i == 0 && blockIdx.x == 0) rp[NT] = E2;
}

__global__ __launch_bounds__(256) void k_fill(const int* __restrict__ ei, const int* __restrict__ rp,
                                              int* __restrict__ fill, int* __restrict__ col) {
    for (int e = blockIdx.x * 256 + threadIdx.x; e < EG; e += gridDim.x * 256) {
        int s = ei[e], d = ei[e + EG];
        int slot1 = rp[d] + atomicAdd(&fill[d], 1);
        col[slot1] = s;
        int slot2 = rp[s] + atomicAdd(&fill[s], 1);
        col[slot2] = d;
    }
}

// ---------------- Weight conversion: fp32 -> bf16, stacked/padded ----------------
__global__ __launch_bounds__(256) void k_wcvt(const float* __restrict__ W1l, const float* __restrict__ W1r,
                                              const float* __restrict__ W2l, const float* __restrict__ W2r,
                                              const float* __restrict__ Wu, const float* __restrict__ Wp,
                                              bf16* __restrict__ B) {
    int i = blockIdx.x * 256 + threadIdx.x;
    if (i < 65536) {
        int layer = i >> 15, rem = i & 32767, o = rem >> 8, k = rem & 255;
        const float* W = layer ? ((k < 128) ? W2l : W2r) : ((k < 128) ? W1l : W1r);
        B[i] = __float2bfloat16(W[o * 128 + (k & 127)]);
    } else if (i < 81920) {
        int rem = i - 65536, o = rem >> 7, k = rem & 127;
        B[i] = __float2bfloat16((k < 100) ? Wu[o * 100 + k] : 0.f);
    } else if (i < 90112) {
        int rem = i - 81920, o = rem >> 6, k = rem & 63;
        B[i] = __float2bfloat16((k < 50) ? Wp[o * 50 + k] : 0.f);
    }
}

// ---------------- MFMA projection tile (device body) ----------------
template<int DIN, int KPAD>
__device__ __forceinline__ void proj_tile(char* As, const float* __restrict__ in,
                                          const bf16* __restrict__ Bp, const float* __restrict__ bias,
                                          bf16* __restrict__ outp, int nrows, int rowbase, int bid) {
    const int tid = threadIdx.x;
    const int tb = bid * 128;
    constexpr int RSTRIDE = KPAD * 2;
    constexpr int PADE = KPAD - DIN;
    constexpr int PH = PADE / 2;
    constexpr int PPAD = 128 * PH;
    constexpr int PMAIN = 128 * DIN / 2;

    for (int q = tid; q < PPAD; q += 256) {
        int row = q / PH;
        int k = DIN + (q - row * PH) * 2;
        *(unsigned*)(As + row * RSTRIDE + ((((k >> 3) << 4) ^ ((row & 7) << 4)) + (k & 7) * 2)) = 0u;
    }
    for (int q = tid; q < PMAIN; q += 256) {
        int f = q * 2;
        int row = f / DIN, k = f - row * DIN;
        int rg = tb + row; if (rg > nrows - 1) rg = nrows - 1;
        float2 v = *(const float2*)(in + (size_t)rg * DIN + k);
        unsigned u = (unsigned)f2bf(v.x) | ((unsigned)f2bf(v.y) << 16);
        *(unsigned*)(As + row * RSTRIDE + ((((k >> 3) << 4) ^ ((row & 7) << 4)) + (k & 7) * 2)) = u;
    }
    __syncthreads();

    const int lane = tid & 63, wid = tid >> 6;
    const int wr = wid >> 1, wc = wid & 1;
    const int r15 = lane & 15, l4 = lane >> 4;
    constexpr int NKS = KPAD / 32;
    f32x4 acc[4][4] = {};
#pragma unroll
    for (int ks = 0; ks < NKS; ks++) {
        short8v a[4], b[4];
#pragma unroll
        for (int m = 0; m < 4; m++) {
            int rl = wr * 64 + m * 16 + r15;
            a[m] = *(const short8v*)(As + rl * RSTRIDE + ((ks * 64 + l4 * 16) ^ ((rl & 7) << 4)));
        }
#pragma unroll
        for (int n = 0; n < 4; n++) {
            int c = wc * 64 + n * 16 + r15;
            b[n] = *(const short8v*)(Bp + (size_t)c * KPAD + ks * 32 + l4 * 8);
        }
#pragma unroll
        for (int m = 0; m < 4; m++)
#pragma unroll
            for (int n = 0; n < 4; n++)
                acc[m][n] = __builtin_amdgcn_mfma_f32_16x16x32_bf16(a[m], b[n], acc[m][n], 0, 0, 0);
    }
    float bcol[4];
#pragma unroll
    for (int n = 0; n < 4; n++) bcol[n] = bias[wc * 64 + n * 16 + r15];
#pragma unroll
    for (int m = 0; m < 4; m++)
#pragma unroll
        for (int n = 0; n < 4; n++)
#pragma unroll
            for (int g = 0; g < 4; g++) {
                int row = tb + wr * 64 + m * 16 + l4 * 4 + g;
                if (row < nrows) {
                    float v = fmaxf(acc[m][n][g] + bcol[n], 0.f);
                    outp[(size_t)(rowbase + row) * HD + wc * 64 + n * 16 + r15] = __float2bfloat16(v);
                }
            }
}

// Combined projection: blocks [0,1563) users, [1563,1954) products
__global__ __launch_bounds__(256) void k_proj2(const float* __restrict__ xu, const float* __restrict__ xp,
                                               const bf16* __restrict__ Bm, const float* __restrict__ bu,
                                               const float* __restrict__ bp, bf16* __restrict__ X) {
    __shared__ __align__(16) char As[32768];
    if (blockIdx.x < 1563)
        proj_tile<100, 128>(As, xu, Bm + 65536, bu, X, NUU, 0, blockIdx.x);
    else
        proj_tile<50, 64>(As, xp, Bm + 81920, bp, X, NPP, NUU, blockIdx.x - 1563);
}

// ---------------- Fused SAGE layer: work-stealing gather -> LDS -> split-K MFMA ----------------
// 128-row tiles; product tiles (1563..1953) interleaved 1-in-5 through dispatch order.
template<bool NORM>
__global__ __launch_bounds__(256) void k_layer(const bf16* __restrict__ hin, const float* __restrict__ ssv,
                                               const int* __restrict__ rp, const int* __restrict__ col,
                                               const bf16* __restrict__ Bmat, const float* __restrict__ blv,
                                               bf16* __restrict__ outp, float* __restrict__ spart,
                                               int store_n) {
    int g = blockIdx.x / 5, pos = blockIdx.x % 5;
    int tile = (pos < 4) ? (g * 4 + pos) : (1563 + g);
    if (pos < 4 && tile > 1562) return;   // only (g=390,pos=3)

    __shared__ __align__(16) char At[32768];   // 128 rows x 256B; slot s: row*256 + ((s*16)^((row&7)<<4))
    __shared__ int rpl[129];
    __shared__ int ctr;
    const int tid = threadIdx.x;
    const int tb = tile * 128;

    if (tid < 129) rpl[tid] = rp[min(tb + tid, NT)];   // clamped: rows >= NT get s0==s1 (deg 0)
    if (tid == 255) ctr = 0;
    __syncthreads();

    // ---- Phase A: work-stealing gather (one node per 8-lane group per pop) ----
    const int lane = tid & 63;
    const int l8 = tid & 7;
    const int fo = l8 * 8;
    float sva[8], tva[8], svb[8], tvb[8];
    if (NORM) {
#pragma unroll
        for (int j = 0; j < 8; j++) {
            sva[j] = ssv[fo + j];      tva[j] = ssv[HD + fo + j];
            svb[j] = ssv[64 + fo + j]; tvb[j] = ssv[HD + 64 + fo + j];
        }
    }
    for (;;) {
        int nl = 0;
        if (l8 == 0) nl = atomicAdd(&ctr, 1);
        nl = __shfl(nl, lane & 56);            // broadcast from group leader
        if (nl >= 128) break;
        int s0 = rpl[nl], s1 = rpl[nl + 1];
        float a[8] = {}, b[8] = {};
        for (int p = s0; p < s1; p += 4) {
            int i1 = min(p + 1, s1 - 1), i2 = min(p + 2, s1 - 1), i3 = min(p + 3, s1 - 1);
            int c0 = col[p], c1 = col[i1], c2 = col[i2], c3 = col[i3];
            const bf16* r0p = hin + (size_t)c0 * HD + fo;
            const bf16* r1p = hin + (size_t)c1 * HD + fo;
            const bf16* r2p = hin + (size_t)c2 * HD + fo;
            const bf16* r3p = hin + (size_t)c3 * HD + fo;
            short8v uA0 = *(const short8v*)r0p, uB0 = *(const short8v*)(r0p + 64);
            short8v uA1 = *(const short8v*)r1p, uB1 = *(const short8v*)(r1p + 64);
            short8v uA2 = *(const short8v*)r2p, uB2 = *(const short8v*)(r2p + 64);
            short8v uA3 = *(const short8v*)r3p, uB3 = *(const short8v*)(r3p + 64);
            float m1 = (p + 1 < s1) ? 1.f : 0.f;
            float m2 = (p + 2 < s1) ? 1.f : 0.f;
            float m3 = (p + 3 < s1) ? 1.f : 0.f;
#pragma unroll
            for (int j = 0; j < 8; j++) {
                float vA0 = b2f(uA0[j]), vA1 = b2f(uA1[j]), vA2 = b2f(uA2[j]), vA3 = b2f(uA3[j]);
                float vB0 = b2f(uB0[j]), vB1 = b2f(uB1[j]), vB2 = b2f(uB2[j]), vB3 = b2f(uB3[j]);
                if (NORM) {
                    vA0 = fmaxf(fmaf(vA0, sva[j], tva[j]), 0.f);
                    vA1 = fmaxf(fmaf(vA1, sva[j], tva[j]), 0.f);
                    vA2 = fmaxf(fmaf(vA2, sva[j], tva[j]), 0.f);
                    vA3 = fmaxf(fmaf(vA3, sva[j], tva[j]), 0.f);
                    vB0 = fmaxf(fmaf(vB0, svb[j], tvb[j]), 0.f);
                    vB1 = fmaxf(fmaf(vB1, svb[j], tvb[j]), 0.f);
                    vB2 = fmaxf(fmaf(vB2, svb[j], tvb[j]), 0.f);
                    vB3 = fmaxf(fmaf(vB3, svb[j], tvb[j]), 0.f);
                }
                a[j] += vA0 + m1 * vA1 + m2 * vA2 + m3 * vA3;
                b[j] += vB0 + m1 * vB1 + m2 * vB2 + m3 * vB3;
            }
        }
        float inv = 1.f / (float)max(s1 - s0, 1);
        short8v wa, wb;
#pragma unroll
        for (int j = 0; j < 8; j++) { wa[j] = (short)f2bf(a[j] * inv); wb[j] = (short)f2bf(b[j] * inv); }
        *(short8v*)(At + nl * 256 + ((l8 * 16) ^ ((nl & 7) << 4))) = wa;
        *(short8v*)(At + nl * 256 + (((8 + l8) * 16) ^ ((nl & 7) << 4))) = wb;
    }

    // ---- Issue own-row loads now; they land during B1 ----
    const int seg = tid & 15, r0 = tid >> 4;
    const int sfo = seg * 8;
    short8v vh[8];
#pragma unroll
    for (int it = 0; it < 8; it++) {
        int row = r0 + it * 16;
        int r = tb + row; if (r > NT - 1) r = NT - 1;
        vh[it] = *(const short8v*)(hin + (size_t)r * HD + sfo);
    }
    __syncthreads();

    // ---- B1: MFMA on means (K 0..127) ----
    const int wid = tid >> 6;
    const int wr = wid >> 1, wc = wid & 1;
    const int r15 = lane & 15, l4 = lane >> 4;
    f32x4 acc[4][4] = {};
#pragma unroll
    for (int ks = 0; ks < 4; ks++) {
        short8v a[4], b[4];
#pragma unroll
        for (int m = 0; m < 4; m++) {
            int rl = wr * 64 + m * 16 + r15;
            a[m] = *(const short8v*)(At + rl * 256 + ((ks * 64 + l4 * 16) ^ ((rl & 7) << 4)));
        }
#pragma unroll
        for (int n = 0; n < 4; n++) {
            int c = wc * 64 + n * 16 + r15;
            b[n] = *(const short8v*)(Bmat + (size_t)c * 256 + ks * 32 + l4 * 8);
        }
#pragma unroll
        for (int m = 0; m < 4; m++)
#pragma unroll
            for (int n = 0; n < 4; n++)
                acc[m][n] = __builtin_amdgcn_mfma_f32_16x16x32_bf16(a[m], b[n], acc[m][n], 0, 0, 0);
    }
    __syncthreads();   // B1 LDS reads done before restage

    // ---- Restage own rows (+BN fold) ----
    if (NORM) {
        float sv2[8], tv2[8];
#pragma unroll
        for (int j = 0; j < 8; j++) { sv2[j] = ssv[sfo + j]; tv2[j] = ssv[HD + sfo + j]; }
#pragma unroll
        for (int it = 0; it < 8; it++) {
#pragma unroll
            for (int j = 0; j < 8; j++) {
                float f = b2f(vh[it][j]);
                vh[it][j] = (short)f2bf(fmaxf(fmaf(f, sv2[j], tv2[j]), 0.f));
            }
        }
    }
#pragma unroll
    for (int it = 0; it < 8; it++) {
        int row = r0 + it * 16;
        *(short8v*)(At + row * 256 + ((seg * 16) ^ ((row & 7) << 4))) = vh[it];
    }
    __syncthreads();

    // ---- B2: MFMA on own rows (K 128..255) ----
#pragma unroll
    for (int ks = 0; ks < 4; ks++) {
        short8v a[4], b[4];
#pragma unroll
        for (int m = 0; m < 4; m++) {
            int rl = wr * 64 + m * 16 + r15;
            a[m] = *(const short8v*)(At + rl * 256 + ((ks * 64 + l4 * 16) ^ ((rl & 7) << 4)));
        }
#pragma unroll
        for (int n = 0; n < 4; n++) {
            int c = wc * 64 + n * 16 + r15;
            b[n] = *(const short8v*)(Bmat + (size_t)c * 256 + (ks + 4) * 32 + l4 * 8);
        }
#pragma unroll
        for (int m = 0; m < 4; m++)
#pragma unroll
            for (int n = 0; n < 4; n++)
                acc[m][n] = __builtin_amdgcn_mfma_f32_16x16x32_bf16(a[m], b[n], acc[m][n], 0, 0, 0);
    }

    // ---- Epilogue: bias, store, BN stats ----
    float bcol[4];
#pragma unroll
    for (int n = 0; n < 4; n++) bcol[n] = blv[wc * 64 + n * 16 + r15];
    float ls[4] = {0.f, 0.f, 0.f, 0.f}, lq[4] = {0.f, 0.f, 0.f, 0.f};
#pragma unroll
    for (int m = 0; m < 4; m++)
#pragma unroll
        for (int n = 0; n < 4; n++)
#pragma unroll
            for (int gg = 0; gg < 4; gg++) {
                int row = tb + wr * 64 + m * 16 + l4 * 4 + gg;
                float v = acc[m][n][gg] + bcol[n];
                if (row < NT) { ls[n] += v; lq[n] += v * v; }
                if (row < store_n)
                    outp[(size_t)row * HD + wc * 64 + n * 16 + r15] = __float2bfloat16(v);
            }
    int part = (tile & 31) * 256;
#pragma unroll
    for (int n = 0; n < 4; n++) {
        float s = ls[n], q2 = lq[n];
        s  += __shfl_xor(s, 16);  s  += __shfl_xor(s, 32);
        q2 += __shfl_xor(q2, 16); q2 += __shfl_xor(q2, 32);
        if (l4 == 0) {
            atomicAdd(&spart[part + wc * 64 + n * 16 + r15], s);
            atomicAdd(&spart[part + 128 + wc * 64 + n * 16 + r15], q2);
        }
    }
}

// ---------------- BN finalize ----------------
__global__ void k_fin(const float* __restrict__ sp, const float* __restrict__ g,
                      const float* __restrict__ be, float* __restrict__ ssout) {
    int j = threadIdx.x;   // 128
    float m = 0.f, q = 0.f;
    for (int i = 0; i < 32; i++) { m += sp[i * 256 + j]; q += sp[i * 256 + 128 + j]; }
    m *= (1.f / (float)NT);
    q = q * (1.f / (float)NT) - m * m;
    float s = g[j] * rsqrtf(q + 1e-5f);
    ssout[j] = s;
    ssout[HD + j] = be[j] - m * s;
}

// ---------------- Final: out = (relu(bn(raw2)) + x)[:NU] @ Wout^T + bout ----------------
__global__ __launch_bounds__(256) void k_out(const bf16* __restrict__ r2, const float* __restrict__ ss,
                                             const bf16* __restrict__ x, const float* __restrict__ wout,
                                             const float* __restrict__ bout, float* __restrict__ outp) {
    int lane = threadIdx.x & 63;
    int wv = (blockIdx.x * blockDim.x + threadIdx.x) >> 6;
    int nwv = (gridDim.x * blockDim.x) >> 6;
    int g16 = lane >> 4, l16 = lane & 15;
    int fo = l16 * 8;
    float s8[8], t8[8], w8[8];
#pragma unroll
    for (int j = 0; j < 8; j++) {
        s8[j] = ss[fo + j]; t8[j] = ss[HD + fo + j]; w8[j] = wout[fo + j];
    }
    float bo = bout[0];
    for (int r0 = wv * 4; r0 < NUU; r0 += nwv * 4) {
        int row = r0 + g16;
        short8v a  = *(const short8v*)(r2 + (size_t)row * HD + fo);
        short8v xx = *(const short8v*)(x  + (size_t)row * HD + fo);
        float acc = 0.f;
#pragma unroll
        for (int j = 0; j < 8; j++) {
            float h = fmaxf(fmaf(b2f(a[j]), s8[j], t8[j]), 0.f) + b2f(xx[j]);
            acc += h * w8[j];
        }
        acc += __shfl_xor(acc, 1);
        acc += __shfl_xor(acc, 2);
        acc += __shfl_xor(acc, 4);
        acc += __shfl_xor(acc, 8);
        if (l16 == 0) outp[row] = acc + bo;
    }
}

extern "C" void kernel_launch(void* const* d_in, const int* in_sizes, int n_in,
                              void* d_out, int out_size, void* d_ws, size_t ws_size,
                              hipStream_t stream) {
    const float* x_u = (const float*)d_in[0];
    const float* x_p = (const float*)d_in[1];
    const int*   ei  = (const int*)d_in[2];
    const float* W_u = (const float*)d_in[3];
    const float* b_u = (const float*)d_in[4];
    const float* W_p = (const float*)d_in[5];
    const float* b_p = (const float*)d_in[6];
    const float* W1l = (const float*)d_in[7];
    const float* b1l = (const float*)d_in[8];
    const float* W1r = (const float*)d_in[9];
    const float* g1  = (const float*)d_in[10];
    const float* be1 = (const float*)d_in[11];
    const float* W2l = (const float*)d_in[12];
    const float* b2l = (const float*)d_in[13];
    const float* W2r = (const float*)d_in[14];
    const float* g2  = (const float*)d_in[15];
    const float* be2 = (const float*)d_in[16];
    const float* Wout = (const float*)d_in[17];
    const float* bout = (const float*)d_in[18];
    float* out = (float*)d_out;
    char* ws = (char*)d_ws;

    if (ws_size < WS_SPLIT) {   // diagnostic fallback (proven not to trigger in r7)
        k_zero<<<512, 256, 0, stream>>>((int*)d_out, out_size);
        return;
    }

    int*  cnt    = (int*)(ws + CNT2_OFF);
    float* spart = (float*)(ws + SPART2_OFF);
    float* ssbuf = (float*)(ws + SS2_OFF);
    int*  rp     = (int*)(ws + RPTR2_OFF);
    int*  bsum   = (int*)(ws + BSUM2_OFF);
    bf16* Bmat   = (bf16*)(ws + BMAT2_OFF);
    int*  col    = (int*)(ws + COL2_OFF);
    bf16* X      = (bf16*)(ws + X2_OFF);
    bf16* R1     = (bf16*)(ws + R1B_OFF);
    bf16* R2     = (bf16*)(ws + R2B_OFF);

    k_zero<<<1043, 256, 0, stream>>>(cnt, 266896);   // cnt + spart + ss contiguous
    k_wcvt<<<352, 256, 0, stream>>>(W1l, W1r, W2l, W2r, W_u, W_p, Bmat);

    k_count<<<1024, 256, 0, stream>>>(ei, cnt);
    k_scan1<<<NBLK_SCAN, 256, 0, stream>>>(cnt, bsum);
    k_scan2<<<1, 1024, 0, stream>>>(bsum);
    k_scan3<<<NBLK_SCAN, 256, 0, stream>>>(cnt, bsum, rp);
    k_zero<<<977, 256, 0, stream>>>(cnt, NT);
    k_fill<<<1024, 256, 0, stream>>>(ei, rp, cnt, col);

    // Projections (merged launch): blocks 0..1562 users, 1563..1953 products
    k_proj2<<<1954, 256, 0, stream>>>(x_u, x_p, Bmat, b_u, b_p, X);

    // Layer 1 (fused, 128-row tiles, work-stealing gather, product tiles interleaved)
    k_layer<false><<<1955, 256, 0, stream>>>(X, nullptr, rp, col, Bmat, b1l, R1, spart, NT);
    k_fin<<<1, 128, 0, stream>>>(spart, g1, be1, ssbuf);

    // Layer 2
    k_layer<true><<<1955, 256, 0, stream>>>(R1, ssbuf, rp, col, Bmat + 32768, b2l, R2, spart + 8192, NUU);
    k_fin<<<1, 128, 0, stream>>>(spart + 8192, g2, be2, ssbuf + 256);

    k_out<<<2048, 256, 0, stream>>>(R2, ssbuf + 256, X, Wout, bout, out);
}